// Round 13
// baseline (211.805 us; speedup 1.0000x reference)
//
#include <hip/hip_runtime.h>
#include <hip/hip_bf16.h>
#include <math.h>

#define BATCH 4096
#define FEAT 128
#define C_TOTAL 16384
#define OUT_TYPES 512

typedef short bf16x8 __attribute__((ext_vector_type(8)));
typedef float f32x4 __attribute__((ext_vector_type(4)));
typedef unsigned short u16;

typedef const __attribute__((address_space(1))) void cg_void;
typedef __attribute__((address_space(3))) void lds_void_t;

static __device__ __forceinline__ u16 f2bf(float f) {
    __hip_bfloat16 h = __float2bfloat16(f);
    return reinterpret_cast<u16&>(h);
}

// ---------------- prologue: out=bias bcast | centres prep | x prep -----------
__global__ void prologue_kernel(const float* __restrict__ x, const float* __restrict__ centres,
                                const float* __restrict__ ls, const float* __restrict__ bias,
                                u16* __restrict__ xb, u16* __restrict__ cbb,
                                float* __restrict__ cc, float* __restrict__ scale,
                                float* __restrict__ hc, float* __restrict__ xx,
                                float* __restrict__ out) {
    const int b = blockIdx.x;
    const int t = threadIdx.x;
    if (b < 2048) {                       // out[m][n] = bias[n], 8 MB
        int i = b * 256 + t;              // float4 index
        float4 bv = reinterpret_cast<const float4*>(bias)[i & 127];
        reinterpret_cast<float4*>(out)[i] = bv;
        return;
    }
    const bool is_c = (b < 2048 + 256);
    const int row = (is_c ? (b - 2048) : (b - 2304)) * 64 + (t >> 2);
    const int l4 = t & 3;
    const float* src = is_c ? centres : x;
    u16* dstb = is_c ? cbb : xb;
    const float4* p = reinterpret_cast<const float4*>(src + (size_t)row * FEAT);
    ushort4* q = reinterpret_cast<ushort4*>(dstb + (size_t)row * FEAT);
    float s = 0.f;
#pragma unroll
    for (int i = 0; i < 8; ++i) {
        float4 v = p[i * 4 + l4];
        s += v.x * v.x + v.y * v.y + v.z * v.z + v.w * v.w;
        ushort4 h;
        h.x = f2bf(v.x); h.y = f2bf(v.y); h.z = f2bf(v.z); h.w = f2bf(v.w);
        q[i * 4 + l4] = h;
    }
    s += __shfl_xor(s, 1);
    s += __shfl_xor(s, 2);
    if (l4 == 0) {
        if (is_c) {
            cc[row] = s;
            scale[row] = __expf(2.f * ls[row]);
            // exact fire condition: sqd*scale < 96 <=> d - 0.5*xx > 0.5*cc - 48/scale
            hc[row] = 0.5f * s - 48.f * __expf(-2.f * ls[row]);
        } else {
            xx[row] = s;
        }
    }
}

// ---------------- rbf ABLATION: template<MODE>, REP reps ---------------------
// MODE 0: full r12 kernel (staging + ds_read + MFMA + screen + cold path).
// MODE 1: MFMA+screen only (register B; acc carried across iters, no CSE).
// MODE 2: staging + vmcnt + ds_read only (XOR checksum keep-alive).
// MODE 3: staging + vmcnt only.
// Only MODE 0 can ever write out (cold path, never fires on this data) ->
// extra variants are output-neutral; each gets its own rocprof dispatch row.
#define BM 128
#define BNW 16
#define NIT 16
#define CSPLIT 16
#define REP 4

template<int MODE>
__global__ __launch_bounds__(256, 2)
void rbf_kernel(const u16* __restrict__ xb, const u16* __restrict__ cb,
                const float* __restrict__ hc, const float* __restrict__ cc,
                const float* __restrict__ scale, const int* __restrict__ node_id,
                const float* __restrict__ xx, const float* __restrict__ W,
                float* __restrict__ out) {
    __shared__ u16 cs[4][4][BNW * FEAT];  // [wave][buf][4 KB]

    const int t = threadIdx.x;
    const int lane = t & 63;
    const int w = t >> 6;
    const int q = lane >> 4;
    const int r = lane & 15;
    const int bid = blockIdx.x;
    const int nid = (bid & 7) * 64 + (bid >> 3);
    const int row0 = (nid & 31) * BM;
    const int cw0 = (nid >> 5) * 1024 + w * (BNW * NIT);
    const int swz = r & 7;

    // ---- setup (identical in all modes) ----
    bf16x8 af[8][4];
#pragma unroll
    for (int m = 0; m < 8; ++m) {
        const u16* xrow = xb + (size_t)(row0 + m * 16 + r) * FEAT + q * 8;
#pragma unroll
        for (int ks = 0; ks < 4; ++ks)
            af[m][ks] = *reinterpret_cast<const bf16x8*>(xrow + ks * 32);
    }
    float nx4[8];
#pragma unroll
    for (int m = 0; m < 8; ++m) {
        float4 v = *reinterpret_cast<const float4*>(&xx[row0 + m * 16 + q * 4]);
        nx4[m] = -0.5f * fminf(fminf(v.x, v.y), fminf(v.z, v.w));
    }
    float hv[NIT];
#pragma unroll
    for (int it = 0; it < NIT; ++it)
        hv[it] = hc[cw0 + it * BNW + r];

    // keep setup alive in modes that don't consume it (anti-DCE, rule #17)
    if constexpr (MODE == 2 || MODE == 3) {
        bf16x8 chk = af[0][0];
#pragma unroll
        for (int m = 0; m < 8; ++m)
#pragma unroll
            for (int ks = 0; ks < 4; ++ks)
                chk ^= af[m][ks];
        int c0 = (int)(short)(chk[0] ^ chk[7]);
        float hs = 0.f;
#pragma unroll
        for (int it = 0; it < NIT; ++it) hs += hv[it];
#pragma unroll
        for (int m = 0; m < 8; ++m) hs += nx4[m];
        asm volatile("" :: "v"(c0), "v"(hs));
    }

#define STAGE(IT, BUF)                                                         \
    {                                                                          \
        _Pragma("unroll")                                                      \
        for (int p = 0; p < 4; ++p) {                                          \
            int G = lane + p * 64;                                             \
            int rr = G >> 4;                                                   \
            int gsrc = (G & 15) ^ (rr & 7);                                    \
            __builtin_amdgcn_global_load_lds(                                  \
                (cg_void*)(cb + (size_t)(cw0 + (IT) * BNW + rr) * FEAT + gsrc * 8), \
                (lds_void_t*)((char*)cs[w][BUF] + G * 16), 16, 0, 0);          \
        }                                                                      \
    }

    if constexpr (MODE == 0) {
        unsigned sus = 0;
#pragma unroll 1
        for (int rep = 0; rep < REP; ++rep) {
            STAGE(0, 0)
            STAGE(1, 1)
#pragma unroll
            for (int it = 0; it < NIT; ++it) {
                if (it + 2 < NIT) STAGE(it + 2, (it + 2) & 3)
                if (it + 2 < NIT)      asm volatile("s_waitcnt vmcnt(8)" ::: "memory");
                else if (it + 1 < NIT) asm volatile("s_waitcnt vmcnt(4)" ::: "memory");
                else                   asm volatile("s_waitcnt vmcnt(0)" ::: "memory");
                __builtin_amdgcn_sched_barrier(0);
                const u16* brow = cs[w][it & 3] + r * FEAT;
                f32x4 acc[8];
#pragma unroll
                for (int m = 0; m < 8; ++m)
                    acc[m] = f32x4{nx4[m], nx4[m], nx4[m], nx4[m]};
                __builtin_amdgcn_s_setprio(1);
#pragma unroll
                for (int ks = 0; ks < 4; ++ks) {
                    int gk = (ks * 4 + q) ^ swz;
                    bf16x8 bf = *reinterpret_cast<const bf16x8*>(brow + gk * 8);
#pragma unroll
                    for (int m = 0; m < 8; ++m)
                        acc[m] = __builtin_amdgcn_mfma_f32_16x16x32_bf16(af[m][ks], bf, acc[m], 0, 0, 0);
                }
                __builtin_amdgcn_s_setprio(0);
                const float hvi = hv[it];
                int fire = 0;
#pragma unroll
                for (int m = 0; m < 8; ++m) {
                    float pm = fmaxf(fmaxf(acc[m][0], acc[m][1]), fmaxf(acc[m][2], acc[m][3]));
                    fire |= (pm > hvi) ? 1 : 0;
                }
                sus |= ((unsigned)fire) << it;
            }
        }
        // cold exact path (never fires on this data; correct if it does)
        if (__builtin_expect(__any((int)(sus != 0u)), 0)) {
            for (int it = 0; it < NIT; ++it) {
                if (!__any((int)(sus & (1u << it)))) continue;
                const u16* p = cb + (size_t)(cw0 + it * BNW + r) * FEAT + q * 8;
                bf16x8 cf[4];
#pragma unroll
                for (int ks = 0; ks < 4; ++ks)
                    cf[ks] = *reinterpret_cast<const bf16x8*>(p + ks * 32);
                f32x4 acc[8];
#pragma unroll
                for (int m = 0; m < 8; ++m) acc[m] = f32x4{0.f, 0.f, 0.f, 0.f};
#pragma unroll
                for (int ks = 0; ks < 4; ++ks)
#pragma unroll
                    for (int m = 0; m < 8; ++m)
                        acc[m] = __builtin_amdgcn_mfma_f32_16x16x32_bf16(af[m][ks], cf[ks], acc[m], 0, 0, 0);
                const int c = cw0 + it * BNW + r;
                const float ccv = cc[c], sv = scale[c];
                const int nd = node_id[c];
#pragma unroll
                for (int m = 0; m < 8; ++m) {
#pragma unroll
                    for (int j = 0; j < 4; ++j) {
                        const int row = row0 + m * 16 + q * 4 + j;
                        float sqd = fmaxf(xx[row] + ccv - 2.f * acc[m][j], 0.f);
                        float tt = sqd * sv;
                        if (tt < 96.f) {
                            float phi = __expf(-tt);
                            float* orow = out + (size_t)row * OUT_TYPES;
                            const float* wcp = W + nd;
                            for (int n = 0; n < OUT_TYPES; ++n)
                                atomicAdd(&orow[n], phi * wcp[(size_t)n * OUT_TYPES]);
                        }
                    }
                }
            }
        }
    }

    if constexpr (MODE == 1) {            // MFMA + screen, register-only B
        unsigned sus = 0;
        f32x4 acc[8];
#pragma unroll
        for (int m = 0; m < 8; ++m)
            acc[m] = f32x4{nx4[m], nx4[m], nx4[m], nx4[m]};
#pragma unroll 1
        for (int rep = 0; rep < REP; ++rep) {
#pragma unroll
            for (int it = 0; it < NIT; ++it) {
                __builtin_amdgcn_s_setprio(1);
#pragma unroll
                for (int ks = 0; ks < 4; ++ks) {
                    bf16x8 bf = af[(2 * ks + 1) & 7][ks];
#pragma unroll
                    for (int m = 0; m < 8; ++m)
                        acc[m] = __builtin_amdgcn_mfma_f32_16x16x32_bf16(af[m][ks], bf, acc[m], 0, 0, 0);
                }
                __builtin_amdgcn_s_setprio(0);
                const float hvi = hv[it];
                int fire = 0;
#pragma unroll
                for (int m = 0; m < 8; ++m) {
                    float pm = fmaxf(fmaxf(acc[m][0], acc[m][1]), fmaxf(acc[m][2], acc[m][3]));
                    fire |= (pm > hvi) ? 1 : 0;
                }
                sus |= ((unsigned)fire) << it;
            }
        }
        asm volatile("" :: "v"(sus));
    }

    if constexpr (MODE == 2) {            // staging + vmcnt + ds_read
        bf16x8 accx = {0, 0, 0, 0, 0, 0, 0, 0};
#pragma unroll 1
        for (int rep = 0; rep < REP; ++rep) {
            STAGE(0, 0)
            STAGE(1, 1)
#pragma unroll
            for (int it = 0; it < NIT; ++it) {
                if (it + 2 < NIT) STAGE(it + 2, (it + 2) & 3)
                if (it + 2 < NIT)      asm volatile("s_waitcnt vmcnt(8)" ::: "memory");
                else if (it + 1 < NIT) asm volatile("s_waitcnt vmcnt(4)" ::: "memory");
                else                   asm volatile("s_waitcnt vmcnt(0)" ::: "memory");
                __builtin_amdgcn_sched_barrier(0);
                const u16* brow = cs[w][it & 3] + r * FEAT;
#pragma unroll
                for (int ks = 0; ks < 4; ++ks) {
                    int gk = (ks * 4 + q) ^ swz;
                    bf16x8 bf = *reinterpret_cast<const bf16x8*>(brow + gk * 8);
                    accx ^= bf;
                }
            }
        }
        int k0 = (int)(short)(accx[0] ^ accx[3] ^ accx[5]);
        asm volatile("" :: "v"(k0));
    }

    if constexpr (MODE == 3) {            // staging + vmcnt only
#pragma unroll 1
        for (int rep = 0; rep < REP; ++rep) {
            STAGE(0, 0)
            STAGE(1, 1)
#pragma unroll
            for (int it = 0; it < NIT; ++it) {
                if (it + 2 < NIT) STAGE(it + 2, (it + 2) & 3)
                if (it + 2 < NIT)      asm volatile("s_waitcnt vmcnt(8)" ::: "memory");
                else if (it + 1 < NIT) asm volatile("s_waitcnt vmcnt(4)" ::: "memory");
                else                   asm volatile("s_waitcnt vmcnt(0)" ::: "memory");
                __builtin_amdgcn_sched_barrier(0);
            }
        }
    }
#undef STAGE
}

// ---------------- launch ------------------------------------------------------
extern "C" void kernel_launch(void* const* d_in, const int* in_sizes, int n_in,
                              void* d_out, int out_size, void* d_ws, size_t ws_size,
                              hipStream_t stream) {
    const float* x       = (const float*)d_in[0];
    const float* centres = (const float*)d_in[1];
    const float* ls      = (const float*)d_in[2];
    const int*   node_id = (const int*)d_in[3];
    const float* W       = (const float*)d_in[4];
    const float* bias    = (const float*)d_in[5];
    float* out = (float*)d_out;

    char* p = (char*)d_ws;
    u16*   xb    = (u16*)p;    p += (size_t)BATCH * FEAT * 2;
    u16*   cbb   = (u16*)p;    p += (size_t)C_TOTAL * FEAT * 2;
    float* cc    = (float*)p;  p += (size_t)C_TOTAL * 4;
    float* scale = (float*)p;  p += (size_t)C_TOTAL * 4;
    float* hc    = (float*)p;  p += (size_t)C_TOTAL * 4;
    float* xx    = (float*)p;  p += (size_t)BATCH * 4;

    hipLaunchKernelGGL(prologue_kernel, dim3(2048 + 256 + 64), dim3(256), 0, stream,
                       x, centres, ls, bias, xb, cbb, cc, scale, hc, xx, out);
    dim3 grid((BATCH / BM) * CSPLIT);
    hipLaunchKernelGGL((rbf_kernel<0>), grid, dim3(256), 0, stream,
                       xb, cbb, hc, cc, scale, node_id, xx, W, out);
    hipLaunchKernelGGL((rbf_kernel<1>), grid, dim3(256), 0, stream,
                       xb, cbb, hc, cc, scale, node_id, xx, W, out);
    hipLaunchKernelGGL((rbf_kernel<2>), grid, dim3(256), 0, stream,
                       xb, cbb, hc, cc, scale, node_id, xx, W, out);
    hipLaunchKernelGGL((rbf_kernel<3>), grid, dim3(256), 0, stream,
                       xb, cbb, hc, cc, scale, node_id, xx, W, out);
}

// Round 14
// 35.767 us; speedup vs baseline: 5.9219x; 5.9219x over previous
//
#include <hip/hip_runtime.h>
#include <hip/hip_bf16.h>
#include <math.h>

#define BATCH 4096
#define FEAT 128
#define C_TOTAL 16384
#define OUT_TYPES 512

typedef short bf16x8 __attribute__((ext_vector_type(8)));
typedef float f32x4 __attribute__((ext_vector_type(4)));
typedef unsigned short u16;

typedef const __attribute__((address_space(1))) void cg_void;
typedef __attribute__((address_space(3))) void lds_void_t;

static __device__ __forceinline__ u16 f2bf(float f) {
    __hip_bfloat16 h = __float2bfloat16(f);
    return reinterpret_cast<u16&>(h);
}

// ---------------- prologue: out=bias bcast | centres prep | x prep -----------
__global__ void prologue_kernel(const float* __restrict__ x, const float* __restrict__ centres,
                                const float* __restrict__ ls, const float* __restrict__ bias,
                                u16* __restrict__ xb, u16* __restrict__ cbb,
                                float* __restrict__ cc, float* __restrict__ scale,
                                float* __restrict__ hc, float* __restrict__ xx,
                                float* __restrict__ out) {
    const int b = blockIdx.x;
    const int t = threadIdx.x;
    if (b < 2048) {                       // out[m][n] = bias[n], 8 MB
        int i = b * 256 + t;              // float4 index
        float4 bv = reinterpret_cast<const float4*>(bias)[i & 127];
        reinterpret_cast<float4*>(out)[i] = bv;
        return;
    }
    const bool is_c = (b < 2048 + 256);
    const int row = (is_c ? (b - 2048) : (b - 2304)) * 64 + (t >> 2);
    const int l4 = t & 3;
    const float* src = is_c ? centres : x;
    u16* dstb = is_c ? cbb : xb;
    const float4* p = reinterpret_cast<const float4*>(src + (size_t)row * FEAT);
    ushort4* q = reinterpret_cast<ushort4*>(dstb + (size_t)row * FEAT);
    float s = 0.f;
#pragma unroll
    for (int i = 0; i < 8; ++i) {
        float4 v = p[i * 4 + l4];
        s += v.x * v.x + v.y * v.y + v.z * v.z + v.w * v.w;
        ushort4 h;
        h.x = f2bf(v.x); h.y = f2bf(v.y); h.z = f2bf(v.z); h.w = f2bf(v.w);
        q[i * 4 + l4] = h;
    }
    s += __shfl_xor(s, 1);
    s += __shfl_xor(s, 2);
    if (l4 == 0) {
        if (is_c) {
            cc[row] = s;
            scale[row] = __expf(2.f * ls[row]);
            // exact fire condition: sqd*scale < 96 <=> d - 0.5*xx > 0.5*cc - 48/scale
            hc[row] = 0.5f * s - 48.f * __expf(-2.f * ls[row]);
        } else {
            xx[row] = s;
        }
    }
}

// ---------------- rbf: wave-autonomous MFMA, identity block mapping ----------
// Identical to round-12 kernel EXCEPT the block->work mapping: identity with
// ROWBLOCK-FAST ordering (row0 = bid&31, chunk = bid>>5). Consecutive bids
// share one centre-chunk, so per-XCD instantaneous L2 working set is <= 2
// chunks (512 KB) + xb REGARDLESS of the physical bid->XCD mapping (the r12
// remap assumed round-robin; if wrong it spreads all 16 chunks over every
// XCD -> 5 MB working set > 4 MB L2 -> staging lands in L3 at ~600-1000 cy,
// which the 2-iter lead can't cover — the r13-measured 30 MB/rep L2-miss).
// 256 thr / 4 independent waves, zero barriers; wave stages its own 16-centre
// tile (4 KB) into private LDS quarter, 4-buf rotation, STAGE(it+2) then
// counted vmcnt(8). Wave-tile 128x16 (af[8][4]); tight screen (per-iter hv,
// per-m nx4); cold exact path post-loop via bitmask.
#define BM 128
#define BNW 16                    /* centres per wave-iter */
#define NIT 16                    /* iters -> 256 centres per wave */
#define CSPLIT 16                 /* 16 chunks of 1024 centres (4 waves) */

__global__ __launch_bounds__(256, 2)
void rbf_kernel(const u16* __restrict__ xb, const u16* __restrict__ cb,
                const float* __restrict__ hc, const float* __restrict__ cc,
                const float* __restrict__ scale, const int* __restrict__ node_id,
                const float* __restrict__ xx, const float* __restrict__ W,
                float* __restrict__ out) {
    __shared__ u16 cs[4][4][BNW * FEAT];  // [wave][buf][4 KB]

    const int t = threadIdx.x;
    const int lane = t & 63;
    const int w = t >> 6;                 // wave 0..3 (independent)
    const int q = lane >> 4;              // 0..3
    const int r = lane & 15;
    // IDENTITY mapping, rowblock-fast: bids 32c..32c+31 all work on chunk c.
    const int bid = blockIdx.x;
    const int row0 = (bid & 31) * BM;
    const int cw0 = (bid >> 5) * 1024 + w * (BNW * NIT);  // wave's 256 centres
    const int swz = r & 7;

    // ---- setup: all global metadata consumed before staging ----
    bf16x8 af[8][4];
#pragma unroll
    for (int m = 0; m < 8; ++m) {
        const u16* xrow = xb + (size_t)(row0 + m * 16 + r) * FEAT + q * 8;
#pragma unroll
        for (int ks = 0; ks < 4; ++ks)
            af[m][ks] = *reinterpret_cast<const bf16x8*>(xrow + ks * 32);
    }
    // per-m acc bias: -0.5 * min(xx) over the 4 rows this lane owns in group m
    float nx4[8];
#pragma unroll
    for (int m = 0; m < 8; ++m) {
        float4 v = *reinterpret_cast<const float4*>(&xx[row0 + m * 16 + q * 4]);
        nx4[m] = -0.5f * fminf(fminf(v.x, v.y), fminf(v.z, v.w));
    }
    // per-iter per-lane threshold (exact hc of this lane's centre)
    float hv[NIT];
#pragma unroll
    for (int it = 0; it < NIT; ++it)
        hv[it] = hc[cw0 + it * BNW + r];

    // ---- per-wave staging: 4 KB tile, 4 loads (linear dest, swz source) ----
#define STAGE(IT, BUF)                                                         \
    {                                                                          \
        _Pragma("unroll")                                                      \
        for (int p = 0; p < 4; ++p) {                                          \
            int G = lane + p * 64;                                             \
            int rr = G >> 4;                                                   \
            int gsrc = (G & 15) ^ (rr & 7);                                    \
            __builtin_amdgcn_global_load_lds(                                  \
                (cg_void*)(cb + (size_t)(cw0 + (IT) * BNW + rr) * FEAT + gsrc * 8), \
                (lds_void_t*)((char*)cs[w][BUF] + G * 16), 16, 0, 0);          \
        }                                                                      \
    }
    STAGE(0, 0)
    STAGE(1, 1)

    unsigned sus = 0;
#pragma unroll
    for (int it = 0; it < NIT; ++it) {
        if (it + 2 < NIT) STAGE(it + 2, (it + 2) & 3)  // buf last read at it-2 (same wave)
        // wait own tile-it loads only (tiles it+1, it+2 stay in flight)
        if (it + 2 < NIT)      asm volatile("s_waitcnt vmcnt(8)" ::: "memory");
        else if (it + 1 < NIT) asm volatile("s_waitcnt vmcnt(4)" ::: "memory");
        else                   asm volatile("s_waitcnt vmcnt(0)" ::: "memory");
        __builtin_amdgcn_sched_barrier(0);

        const u16* brow = cs[w][it & 3] + r * FEAT;
        f32x4 acc[8];
#pragma unroll
        for (int m = 0; m < 8; ++m)
            acc[m] = f32x4{nx4[m], nx4[m], nx4[m], nx4[m]};
        __builtin_amdgcn_s_setprio(1);
#pragma unroll
        for (int ks = 0; ks < 4; ++ks) {
            int gk = (ks * 4 + q) ^ swz;
            bf16x8 bf = *reinterpret_cast<const bf16x8*>(brow + gk * 8);
#pragma unroll
            for (int m = 0; m < 8; ++m)
                acc[m] = __builtin_amdgcn_mfma_f32_16x16x32_bf16(af[m][ks], bf, acc[m], 0, 0, 0);
        }
        __builtin_amdgcn_s_setprio(0);

        // tight screen: per-m max vs per-iter exact threshold
        const float hvi = hv[it];
        int fire = 0;
#pragma unroll
        for (int m = 0; m < 8; ++m) {
            float pm = fmaxf(fmaxf(acc[m][0], acc[m][1]), fmaxf(acc[m][2], acc[m][3]));
            fire |= (pm > hvi) ? 1 : 0;
        }
        sus |= ((unsigned)fire) << it;
    }
#undef STAGE

    // ---- cold exact path (never taken on this data; correct if taken) ----
    if (__builtin_expect(__any((int)(sus != 0u)), 0)) {
        for (int it = 0; it < NIT; ++it) {
            if (!__any((int)(sus & (1u << it)))) continue;
            const u16* p = cb + (size_t)(cw0 + it * BNW + r) * FEAT + q * 8;
            bf16x8 cf[4];
#pragma unroll
            for (int ks = 0; ks < 4; ++ks)
                cf[ks] = *reinterpret_cast<const bf16x8*>(p + ks * 32);
            f32x4 acc[8];
#pragma unroll
            for (int m = 0; m < 8; ++m) acc[m] = f32x4{0.f, 0.f, 0.f, 0.f};
#pragma unroll
            for (int ks = 0; ks < 4; ++ks)
#pragma unroll
                for (int m = 0; m < 8; ++m)
                    acc[m] = __builtin_amdgcn_mfma_f32_16x16x32_bf16(af[m][ks], cf[ks], acc[m], 0, 0, 0);
            const int c = cw0 + it * BNW + r;
            const float ccv = cc[c], sv = scale[c];
            const int nd = node_id[c];
#pragma unroll
            for (int m = 0; m < 8; ++m) {
#pragma unroll
                for (int j = 0; j < 4; ++j) {
                    const int row = row0 + m * 16 + q * 4 + j;
                    float sqd = fmaxf(xx[row] + ccv - 2.f * acc[m][j], 0.f);
                    float tt = sqd * sv;
                    if (tt < 96.f) {
                        float phi = __expf(-tt);
                        float* orow = out + (size_t)row * OUT_TYPES;
                        const float* wcp = W + nd;
                        for (int n = 0; n < OUT_TYPES; ++n)
                            atomicAdd(&orow[n], phi * wcp[(size_t)n * OUT_TYPES]);
                    }
                }
            }
        }
    }
}

// ---------------- launch ------------------------------------------------------
extern "C" void kernel_launch(void* const* d_in, const int* in_sizes, int n_in,
                              void* d_out, int out_size, void* d_ws, size_t ws_size,
                              hipStream_t stream) {
    const float* x       = (const float*)d_in[0];
    const float* centres = (const float*)d_in[1];
    const float* ls      = (const float*)d_in[2];
    const int*   node_id = (const int*)d_in[3];
    const float* W       = (const float*)d_in[4];
    const float* bias    = (const float*)d_in[5];
    float* out = (float*)d_out;

    // ws: xb 1MB | cbb 4MB | cc 64KB | scale 64KB | hc 64KB | xx 16KB
    char* p = (char*)d_ws;
    u16*   xb    = (u16*)p;    p += (size_t)BATCH * FEAT * 2;
    u16*   cbb   = (u16*)p;    p += (size_t)C_TOTAL * FEAT * 2;
    float* cc    = (float*)p;  p += (size_t)C_TOTAL * 4;
    float* scale = (float*)p;  p += (size_t)C_TOTAL * 4;
    float* hc    = (float*)p;  p += (size_t)C_TOTAL * 4;
    float* xx    = (float*)p;  p += (size_t)BATCH * 4;

    hipLaunchKernelGGL(prologue_kernel, dim3(2048 + 256 + 64), dim3(256), 0, stream,
                       x, centres, ls, bias, xb, cbb, cc, scale, hc, xx, out);
    hipLaunchKernelGGL(rbf_kernel, dim3((BATCH / BM) * CSPLIT), dim3(256), 0, stream,
                       xb, cbb, hc, cc, scale, node_id, xx, W, out);
}